// Round 1
// baseline (20136.064 us; speedup 1.0000x reference)
//
#include <hip/hip_runtime.h>
#include <math.h>

#define N_NODES 100000
#define N_EDGES 1600000
#define F_IN    92
#define H_DIM   128
#define STEPS   6
#define G_GRAPHS 256
#define TH3     384   // 3*H

// ---------------- precompute: fused per-step weight M_i = W_mpnn[i] @ w_ih^T ----------------
// M[i][k][j] = sum_c Wmpnn[i][k][c] * w_ih[j][c]     (k in [0,128), j in [0,384))
__global__ void fuse_w_kernel(const float* __restrict__ Wm, const float* __restrict__ w_ih,
                              float* __restrict__ M) {
    int ik = blockIdx.x;            // 6*128 blocks
    int i  = ik >> 7;
    int k  = ik & 127;
    int j  = threadIdx.x;           // 384 threads
    __shared__ float wrow[H_DIM];
    if (j < H_DIM) wrow[j] = Wm[(i * H_DIM + k) * H_DIM + j];
    __syncthreads();
    float acc = 0.f;
    #pragma unroll 4
    for (int c = 0; c < H_DIM; ++c) acc += wrow[c] * w_ih[j * H_DIM + c];
    M[(i * H_DIM + k) * TH3 + j] = acc;
}

// transpose w_hh [384,128] -> whhT [128,384]
__global__ void transp_kernel(const float* __restrict__ w_hh, float* __restrict__ whhT) {
    int idx = blockIdx.x * 256 + threadIdx.x;
    if (idx < TH3 * H_DIM) {
        int j = idx / H_DIM;
        int k = idx - j * H_DIM;
        whhT[k * TH3 + j] = w_hh[idx];
    }
}

// ---------------- embed: h = tanh(x @ W_embed) ----------------
#define ET 16
__global__ void embed_kernel(const float* __restrict__ x, const float* __restrict__ We,
                             float* __restrict__ h) {
    int n0 = blockIdx.x * ET;       // N/ET = 6250 blocks, exact
    int j  = threadIdx.x;           // 128 threads
    __shared__ float xs[ET * F_IN];
    for (int i = j; i < ET * F_IN; i += H_DIM) xs[i] = x[n0 * F_IN + i];
    __syncthreads();
    float acc[ET];
    #pragma unroll
    for (int n = 0; n < ET; ++n) acc[n] = 0.f;
    const float4* xs4 = (const float4*)xs;   // row = 92 floats = 23 float4, 16B aligned
    for (int k4 = 0; k4 < F_IN / 4; ++k4) {
        int k = k4 * 4;
        float w0 = We[(k + 0) * H_DIM + j];
        float w1 = We[(k + 1) * H_DIM + j];
        float w2 = We[(k + 2) * H_DIM + j];
        float w3 = We[(k + 3) * H_DIM + j];
        #pragma unroll
        for (int n = 0; n < ET; ++n) {
            float4 a = xs4[n * (F_IN / 4) + k4];
            acc[n] += a.x * w0 + a.y * w1 + a.z * w2 + a.w * w3;
        }
    }
    #pragma unroll
    for (int n = 0; n < ET; ++n) {
        // fast tanh, overflow-safe: 1 - 2/(e^{2x}+1)
        float e2 = __expf(2.f * acc[n]);
        h[(n0 + n) * H_DIM + j] = 1.f - 2.f / (e2 + 1.f);
    }
}

// ---------------- scatter: s[dst] += h[src]  (per edge, 128 channels) ----------------
__global__ void scatter_kernel(const float4* __restrict__ h4, const int* __restrict__ src,
                               const int* __restrict__ dst, float* __restrict__ s) {
    unsigned tid = blockIdx.x * 256 + threadIdx.x;   // E*32 threads exact
    int e = tid >> 5;
    int c = tid & 31;
    if (e < N_EDGES) {
        int sn = src[e];
        int dn = dst[e];
        float4 v = h4[sn * 32 + c];
        float* p = s + dn * H_DIM + c * 4;
        atomicAdd(p + 0, v.x);
        atomicAdd(p + 1, v.y);
        atomicAdd(p + 2, v.z);
        atomicAdd(p + 3, v.w);
    }
}

// ---------------- fused GRU step: gi = s@M_i + b_ih; gh = h@whhT + b_hh; h = GRU ----------------
#define GT 16
__global__ __launch_bounds__(384) void gru_kernel(const float* __restrict__ s,
                                                  float* __restrict__ h,
                                                  const float* __restrict__ Mi,
                                                  const float* __restrict__ whhT,
                                                  const float* __restrict__ b_ih,
                                                  const float* __restrict__ b_hh) {
    int n0 = blockIdx.x * GT;       // 6250 blocks, exact
    int j  = threadIdx.x;           // 384 threads
    __shared__ float As[GT * H_DIM];   // s rows   8KB
    __shared__ float Ah[GT * H_DIM];   // h rows   8KB
    __shared__ float Srz[GT * 256];    // r,z preact sums 16KB
    __shared__ float Sin[GT * H_DIM];  // i_n  8KB
    __shared__ float Shn[GT * H_DIM];  // h_n  8KB

    for (int i = j; i < GT * H_DIM; i += TH3) {
        As[i] = s[n0 * H_DIM + i];
        Ah[i] = h[n0 * H_DIM + i];
    }
    __syncthreads();

    float accI[GT], accH[GT];
    #pragma unroll
    for (int n = 0; n < GT; ++n) { accI[n] = 0.f; accH[n] = 0.f; }

    const float4* As4 = (const float4*)As;
    const float4* Ah4 = (const float4*)Ah;
    for (int k4 = 0; k4 < H_DIM / 4; ++k4) {
        int k = k4 * 4;
        float m0 = Mi[(k + 0) * TH3 + j];
        float m1 = Mi[(k + 1) * TH3 + j];
        float m2 = Mi[(k + 2) * TH3 + j];
        float m3 = Mi[(k + 3) * TH3 + j];
        float w0 = whhT[(k + 0) * TH3 + j];
        float w1 = whhT[(k + 1) * TH3 + j];
        float w2 = whhT[(k + 2) * TH3 + j];
        float w3 = whhT[(k + 3) * TH3 + j];
        #pragma unroll
        for (int n = 0; n < GT; ++n) {
            float4 a = As4[n * (H_DIM / 4) + k4];
            float4 b = Ah4[n * (H_DIM / 4) + k4];
            accI[n] += a.x * m0 + a.y * m1 + a.z * m2 + a.w * m3;
            accH[n] += b.x * w0 + b.y * w1 + b.z * w2 + b.w * w3;
        }
    }

    float bi = b_ih[j];
    float bh = b_hh[j];
    if (j < 256) {                                   // waves 0-3: r,z gate preact sums
        #pragma unroll
        for (int n = 0; n < GT; ++n) Srz[n * 256 + j] = (accI[n] + bi) + (accH[n] + bh);
    } else {                                         // waves 4-5: candidate parts, kept separate
        int jj = j - 256;
        #pragma unroll
        for (int n = 0; n < GT; ++n) {
            Sin[n * H_DIM + jj] = accI[n] + bi;
            Shn[n * H_DIM + jj] = accH[n] + bh;
        }
    }
    __syncthreads();

    for (int idx = j; idx < GT * H_DIM; idx += TH3) {
        int n = idx >> 7;
        int c = idx & 127;
        float r = 1.f / (1.f + __expf(-Srz[n * 256 + c]));
        float z = 1.f / (1.f + __expf(-Srz[n * 256 + 128 + c]));
        float pre = Sin[n * H_DIM + c] + r * Shn[n * H_DIM + c];
        float e2 = __expf(2.f * pre);
        float cand = 1.f - 2.f / (e2 + 1.f);        // tanh, overflow-safe
        float hold = Ah[idx];
        h[n0 * H_DIM + idx] = (1.f - z) * cand + z * hold;
    }
}

// ---------------- pool + relu + prediction head ----------------
__global__ void pool_kernel(const float* __restrict__ h, const int* __restrict__ batch,
                            const float* __restrict__ w_pred, const float* __restrict__ b_pred,
                            float* __restrict__ out) {
    int g = blockIdx.x;             // 256 blocks
    int t = threadIdx.x;            // 128 threads
    __shared__ int bounds[2];
    __shared__ float red[2];
    if (t < 2) {                    // lower_bound(batch, g) and lower_bound(batch, g+1)
        int target = g + t;
        int lo = 0, hi = N_NODES;
        while (lo < hi) {
            int mid = (lo + hi) >> 1;
            if (batch[mid] < target) lo = mid + 1; else hi = mid;
        }
        bounds[t] = lo;
    }
    __syncthreads();
    int lo = bounds[0], hi = bounds[1];
    float sum = 0.f;
    for (int n = lo; n < hi; ++n) sum += h[n * H_DIM + t];
    int cnt = hi - lo;
    float pooled = sum / fmaxf((float)cnt, 1.f);
    pooled = fmaxf(pooled, 0.f);
    float v = pooled * w_pred[t];
    #pragma unroll
    for (int off = 32; off > 0; off >>= 1) v += __shfl_down(v, off);
    if ((t & 63) == 0) red[t >> 6] = v;
    __syncthreads();
    if (t == 0) out[g] = red[0] + red[1] + b_pred[0];
}

extern "C" void kernel_launch(void* const* d_in, const int* in_sizes, int n_in,
                              void* d_out, int out_size, void* d_ws, size_t ws_size,
                              hipStream_t stream) {
    const float* x      = (const float*)d_in[0];
    const int*   ei     = (const int*)d_in[1];    // [2,E] row-major: src = ei, dst = ei+E
    const int*   batch  = (const int*)d_in[2];
    const float* We     = (const float*)d_in[3];
    const float* Wm     = (const float*)d_in[4];
    const float* w_ih   = (const float*)d_in[5];
    const float* w_hh   = (const float*)d_in[6];
    const float* b_ih   = (const float*)d_in[7];
    const float* b_hh   = (const float*)d_in[8];
    const float* w_pred = (const float*)d_in[9];
    const float* b_pred = (const float*)d_in[10];
    float* out = (float*)d_out;

    float* h    = (float*)d_ws;                        // N*H
    float* s    = h + (size_t)N_NODES * H_DIM;         // N*H
    float* M6   = s + (size_t)N_NODES * H_DIM;         // 6*H*384
    float* whhT = M6 + (size_t)STEPS * H_DIM * TH3;    // H*384

    fuse_w_kernel<<<STEPS * H_DIM, TH3, 0, stream>>>(Wm, w_ih, M6);
    transp_kernel<<<(TH3 * H_DIM + 255) / 256, 256, 0, stream>>>(w_hh, whhT);
    embed_kernel<<<N_NODES / ET, H_DIM, 0, stream>>>(x, We, h);

    for (int i = 0; i < STEPS; ++i) {
        hipMemsetAsync(s, 0, (size_t)N_NODES * H_DIM * sizeof(float), stream);
        scatter_kernel<<<(N_EDGES * 32) / 256, 256, 0, stream>>>((const float4*)h, ei, ei + N_EDGES, s);
        gru_kernel<<<N_NODES / GT, TH3, 0, stream>>>(s, h, M6 + (size_t)i * H_DIM * TH3,
                                                     whhT, b_ih, b_hh);
    }

    pool_kernel<<<G_GRAPHS, H_DIM, 0, stream>>>(h, batch, w_pred, b_pred, out);
}

// Round 2
// 3424.896 us; speedup vs baseline: 5.8793x; 5.8793x over previous
//
#include <hip/hip_runtime.h>
#include <math.h>

#define N_NODES 100000
#define N_EDGES 1600000
#define F_IN    92
#define H_DIM   128
#define STEPS   6
#define G_GRAPHS 256
#define TH3     384   // 3*H

// ---------------- precompute: fused per-step weight M_i = W_mpnn[i] @ w_ih^T ----------------
// M[i][k][j] = sum_c Wmpnn[i][k][c] * w_ih[j][c]     (k in [0,128), j in [0,384))
__global__ void fuse_w_kernel(const float* __restrict__ Wm, const float* __restrict__ w_ih,
                              float* __restrict__ M) {
    int ik = blockIdx.x;            // 6*128 blocks
    int i  = ik >> 7;
    int k  = ik & 127;
    int j  = threadIdx.x;           // 384 threads
    __shared__ float wrow[H_DIM];
    if (j < H_DIM) wrow[j] = Wm[(i * H_DIM + k) * H_DIM + j];
    __syncthreads();
    float acc = 0.f;
    #pragma unroll 4
    for (int c = 0; c < H_DIM; ++c) acc += wrow[c] * w_ih[j * H_DIM + c];
    M[(i * H_DIM + k) * TH3 + j] = acc;
}

// transpose w_hh [384,128] -> whhT [128,384]
__global__ void transp_kernel(const float* __restrict__ w_hh, float* __restrict__ whhT) {
    int idx = blockIdx.x * 256 + threadIdx.x;
    if (idx < TH3 * H_DIM) {
        int j = idx / H_DIM;
        int k = idx - j * H_DIM;
        whhT[k * TH3 + j] = w_hh[idx];
    }
}

// ---------------- embed: h = tanh(x @ W_embed) ----------------
#define ET 16
__global__ void embed_kernel(const float* __restrict__ x, const float* __restrict__ We,
                             float* __restrict__ h) {
    int n0 = blockIdx.x * ET;       // N/ET = 6250 blocks, exact
    int j  = threadIdx.x;           // 128 threads
    __shared__ float xs[ET * F_IN];
    for (int i = j; i < ET * F_IN; i += H_DIM) xs[i] = x[n0 * F_IN + i];
    __syncthreads();
    float acc[ET];
    #pragma unroll
    for (int n = 0; n < ET; ++n) acc[n] = 0.f;
    const float4* xs4 = (const float4*)xs;   // row = 92 floats = 23 float4, 16B aligned
    for (int k4 = 0; k4 < F_IN / 4; ++k4) {
        int k = k4 * 4;
        float w0 = We[(k + 0) * H_DIM + j];
        float w1 = We[(k + 1) * H_DIM + j];
        float w2 = We[(k + 2) * H_DIM + j];
        float w3 = We[(k + 3) * H_DIM + j];
        #pragma unroll
        for (int n = 0; n < ET; ++n) {
            float4 a = xs4[n * (F_IN / 4) + k4];
            acc[n] += a.x * w0 + a.y * w1 + a.z * w2 + a.w * w3;
        }
    }
    #pragma unroll
    for (int n = 0; n < ET; ++n) {
        float e2 = __expf(2.f * acc[n]);
        h[(n0 + n) * H_DIM + j] = 1.f - 2.f / (e2 + 1.f);
    }
}

// ---------------- CSR build: histogram -> scan -> bucket fill ----------------
__global__ void hist_kernel(const int* __restrict__ dst, int* __restrict__ count) {
    int e = blockIdx.x * 256 + threadIdx.x;
    if (e < N_EDGES) atomicAdd(&count[dst[e]], 1);
}

__global__ void scan_block_kernel(const int* __restrict__ count, int* __restrict__ offs,
                                  int* __restrict__ blockSums) {
    __shared__ int tmp[256];
    int i = blockIdx.x * 256 + threadIdx.x;
    int t = threadIdx.x;
    int v = (i < N_NODES) ? count[i] : 0;
    tmp[t] = v;
    __syncthreads();
    for (int d = 1; d < 256; d <<= 1) {          // inclusive Hillis-Steele
        int add = (t >= d) ? tmp[t - d] : 0;
        __syncthreads();
        tmp[t] += add;
        __syncthreads();
    }
    if (i < N_NODES) offs[i] = tmp[t] - v;       // exclusive within block
    if (t == 255) blockSums[blockIdx.x] = tmp[255];
}

__global__ void scan_sums_kernel(int* __restrict__ blockSums, int nb) {  // 1 block, 512 thr
    __shared__ int tmp[512];
    int t = threadIdx.x;
    int v = (t < nb) ? blockSums[t] : 0;
    tmp[t] = v;
    __syncthreads();
    for (int d = 1; d < 512; d <<= 1) {
        int add = (t >= d) ? tmp[t - d] : 0;
        __syncthreads();
        tmp[t] += add;
        __syncthreads();
    }
    if (t < nb) blockSums[t] = tmp[t] - v;       // exclusive
}

__global__ void scan_add_kernel(int* __restrict__ offs, const int* __restrict__ blockSums) {
    int i = blockIdx.x * 256 + threadIdx.x;
    if (i < N_NODES) offs[i] += blockSums[blockIdx.x];
    if (i == 0) offs[N_NODES] = N_EDGES;
}

__global__ void fill_kernel(const int* __restrict__ src, const int* __restrict__ dst,
                            const int* __restrict__ offs, int* __restrict__ cursor,
                            int* __restrict__ srcSorted) {
    int e = blockIdx.x * 256 + threadIdx.x;
    if (e < N_EDGES) {
        int d = dst[e];
        int pos = atomicAdd(&cursor[d], 1);
        srcSorted[offs[d] + pos] = src[e];
    }
}

// ---------------- gather: s[n] = sum over incoming edges of h[src] ----------------
__global__ void gather_kernel(const float4* __restrict__ h4, const int* __restrict__ offs,
                              const int* __restrict__ srcSorted, float4* __restrict__ s4) {
    int tid  = blockIdx.x * 256 + threadIdx.x;   // N/8 = 12500 blocks, exact
    int node = tid >> 5;
    int c    = tid & 31;
    int beg = offs[node], end = offs[node + 1];
    float4 acc = make_float4(0.f, 0.f, 0.f, 0.f);
    int i = beg;
    for (; i + 4 <= end; i += 4) {               // 4 loads in flight per iter
        int s0 = srcSorted[i], s1 = srcSorted[i + 1];
        int s2 = srcSorted[i + 2], s3 = srcSorted[i + 3];
        float4 v0 = h4[(size_t)s0 * 32 + c];
        float4 v1 = h4[(size_t)s1 * 32 + c];
        float4 v2 = h4[(size_t)s2 * 32 + c];
        float4 v3 = h4[(size_t)s3 * 32 + c];
        acc.x += v0.x + v1.x + v2.x + v3.x;
        acc.y += v0.y + v1.y + v2.y + v3.y;
        acc.z += v0.z + v1.z + v2.z + v3.z;
        acc.w += v0.w + v1.w + v2.w + v3.w;
    }
    for (; i < end; ++i) {
        int sn = srcSorted[i];
        float4 v = h4[(size_t)sn * 32 + c];
        acc.x += v.x; acc.y += v.y; acc.z += v.z; acc.w += v.w;
    }
    s4[(size_t)node * 32 + c] = acc;
}

// ---------------- fused GRU step: thread t owns gate columns t, t+128, t+256 ----------------
#define GT 16
__global__ __launch_bounds__(128) void gru_kernel(const float* __restrict__ s,
                                                  float* __restrict__ h,
                                                  const float* __restrict__ Mi,
                                                  const float* __restrict__ whhT,
                                                  const float* __restrict__ b_ih,
                                                  const float* __restrict__ b_hh) {
    int n0 = blockIdx.x * GT;       // 6250 blocks, exact
    int t  = threadIdx.x;           // 128 threads
    __shared__ float As[GT * H_DIM];   // s rows   8KB
    __shared__ float Ah[GT * H_DIM];   // h rows   8KB

    for (int i = t; i < GT * H_DIM; i += H_DIM) {
        As[i] = s[n0 * H_DIM + i];
        Ah[i] = h[n0 * H_DIM + i];
    }
    __syncthreads();

    float aIr[GT], aIz[GT], aIn[GT], aHr[GT], aHz[GT], aHn[GT];
    #pragma unroll
    for (int n = 0; n < GT; ++n) {
        aIr[n] = 0.f; aIz[n] = 0.f; aIn[n] = 0.f;
        aHr[n] = 0.f; aHz[n] = 0.f; aHn[n] = 0.f;
    }

    const float4* As4 = (const float4*)As;
    const float4* Ah4 = (const float4*)Ah;
    for (int k4 = 0; k4 < H_DIM / 4; ++k4) {
        int k = k4 * 4;
        float mr[4], mz[4], mn[4], wr[4], wz[4], wn[4];
        #pragma unroll
        for (int kk = 0; kk < 4; ++kk) {
            const float* Mrow = Mi + (k + kk) * TH3;
            mr[kk] = Mrow[t]; mz[kk] = Mrow[t + 128]; mn[kk] = Mrow[t + 256];
            const float* Wrow = whhT + (k + kk) * TH3;
            wr[kk] = Wrow[t]; wz[kk] = Wrow[t + 128]; wn[kk] = Wrow[t + 256];
        }
        #pragma unroll
        for (int n = 0; n < GT; ++n) {
            float4 a = As4[n * (H_DIM / 4) + k4];
            float4 b = Ah4[n * (H_DIM / 4) + k4];
            aIr[n] += a.x * mr[0] + a.y * mr[1] + a.z * mr[2] + a.w * mr[3];
            aIz[n] += a.x * mz[0] + a.y * mz[1] + a.z * mz[2] + a.w * mz[3];
            aIn[n] += a.x * mn[0] + a.y * mn[1] + a.z * mn[2] + a.w * mn[3];
            aHr[n] += b.x * wr[0] + b.y * wr[1] + b.z * wr[2] + b.w * wr[3];
            aHz[n] += b.x * wz[0] + b.y * wz[1] + b.z * wz[2] + b.w * wz[3];
            aHn[n] += b.x * wn[0] + b.y * wn[1] + b.z * wn[2] + b.w * wn[3];
        }
    }

    float bir = b_ih[t], biz = b_ih[t + 128], bin = b_ih[t + 256];
    float bhr = b_hh[t], bhz = b_hh[t + 128], bhn = b_hh[t + 256];
    #pragma unroll
    for (int n = 0; n < GT; ++n) {
        float r = 1.f / (1.f + __expf(-((aIr[n] + bir) + (aHr[n] + bhr))));
        float z = 1.f / (1.f + __expf(-((aIz[n] + biz) + (aHz[n] + bhz))));
        float pre = (aIn[n] + bin) + r * (aHn[n] + bhn);
        float e2 = __expf(2.f * pre);
        float cand = 1.f - 2.f / (e2 + 1.f);        // tanh, overflow-safe
        float hold = Ah[n * H_DIM + t];
        h[(n0 + n) * H_DIM + t] = (1.f - z) * cand + z * hold;
    }
}

// ---------------- pool + relu + prediction head ----------------
__global__ void pool_kernel(const float* __restrict__ h, const int* __restrict__ batch,
                            const float* __restrict__ w_pred, const float* __restrict__ b_pred,
                            float* __restrict__ out) {
    int g = blockIdx.x;             // 256 blocks
    int t = threadIdx.x;            // 128 threads
    __shared__ int bounds[2];
    __shared__ float red[2];
    if (t < 2) {
        int target = g + t;
        int lo = 0, hi = N_NODES;
        while (lo < hi) {
            int mid = (lo + hi) >> 1;
            if (batch[mid] < target) lo = mid + 1; else hi = mid;
        }
        bounds[t] = lo;
    }
    __syncthreads();
    int lo = bounds[0], hi = bounds[1];
    float sum = 0.f;
    for (int n = lo; n < hi; ++n) sum += h[n * H_DIM + t];
    int cnt = hi - lo;
    float pooled = sum / fmaxf((float)cnt, 1.f);
    pooled = fmaxf(pooled, 0.f);
    float v = pooled * w_pred[t];
    #pragma unroll
    for (int off = 32; off > 0; off >>= 1) v += __shfl_down(v, off);
    if ((t & 63) == 0) red[t >> 6] = v;
    __syncthreads();
    if (t == 0) out[g] = red[0] + red[1] + b_pred[0];
}

extern "C" void kernel_launch(void* const* d_in, const int* in_sizes, int n_in,
                              void* d_out, int out_size, void* d_ws, size_t ws_size,
                              hipStream_t stream) {
    const float* x      = (const float*)d_in[0];
    const int*   ei     = (const int*)d_in[1];    // [2,E]: src = ei, dst = ei+E
    const int*   batch  = (const int*)d_in[2];
    const float* We     = (const float*)d_in[3];
    const float* Wm     = (const float*)d_in[4];
    const float* w_ih   = (const float*)d_in[5];
    const float* w_hh   = (const float*)d_in[6];
    const float* b_ih   = (const float*)d_in[7];
    const float* b_hh   = (const float*)d_in[8];
    const float* w_pred = (const float*)d_in[9];
    const float* b_pred = (const float*)d_in[10];
    float* out = (float*)d_out;

    float* h    = (float*)d_ws;                        // N*H = 12.8M floats
    float* s    = h + (size_t)N_NODES * H_DIM;         // N*H
    float* M6   = s + (size_t)N_NODES * H_DIM;         // 6*128*384
    float* whhT = M6 + (size_t)STEPS * H_DIM * TH3;    // 128*384
    int* offs      = (int*)(whhT + (size_t)H_DIM * TH3); // N+1 ints
    int* srcSorted = offs + (N_NODES + 1);               // E ints
    // CSR-build temporaries overlaid on s (s only used inside the step loop)
    int* count     = (int*)s;
    int* cursor    = count + N_NODES;
    int* blockSums = cursor + N_NODES;                   // 391 ints

    const int* esrc = ei;
    const int* edst = ei + N_EDGES;
    const int EB = (N_EDGES + 255) / 256;                // 6250
    const int NB = (N_NODES + 255) / 256;                // 391

    // --- build CSR (once per launch) ---
    hipMemsetAsync(count, 0, 2 * (size_t)N_NODES * sizeof(int), stream);  // count + cursor
    hist_kernel<<<EB, 256, 0, stream>>>(edst, count);
    scan_block_kernel<<<NB, 256, 0, stream>>>(count, offs, blockSums);
    scan_sums_kernel<<<1, 512, 0, stream>>>(blockSums, NB);
    scan_add_kernel<<<NB, 256, 0, stream>>>(offs, blockSums);
    fill_kernel<<<EB, 256, 0, stream>>>(esrc, edst, offs, cursor, srcSorted);

    fuse_w_kernel<<<STEPS * H_DIM, TH3, 0, stream>>>(Wm, w_ih, M6);
    transp_kernel<<<(TH3 * H_DIM + 255) / 256, 256, 0, stream>>>(w_hh, whhT);
    embed_kernel<<<N_NODES / ET, H_DIM, 0, stream>>>(x, We, h);

    for (int i = 0; i < STEPS; ++i) {
        gather_kernel<<<N_NODES / 8, 256, 0, stream>>>((const float4*)h, offs, srcSorted,
                                                       (float4*)s);
        gru_kernel<<<N_NODES / GT, H_DIM, 0, stream>>>(s, h, M6 + (size_t)i * H_DIM * TH3,
                                                       whhT, b_ih, b_hh);
    }

    pool_kernel<<<G_GRAPHS, H_DIM, 0, stream>>>(h, batch, w_pred, b_pred, out);
}